// Round 14
// baseline (100.596 us; speedup 1.0000x reference)
//
#include <hip/hip_runtime.h>

#define T_TOTAL 200000
#define NL 49
#define NP 50
#define NB 20
#define THREADS 256
#define WPB 4                        // waves per block
#define TPW 16                       // timesteps per wave
#define NWAVES (T_TOTAL / TPW)       // 12500
#define NBLOCKS (NWAVES / WPB)       // 3125

// Zero-barrier wave-independent kernel: each wave owns 16 timesteps end-to-end.
// 51 angle loads batched (asm-pinned, ONE memory round-trip per 16 timesteps),
// then 17 register shuffle-prefix chains (incl. halo) with inline loss/reg2/
// stores. No LDS data path, no main-path __syncthreads.
__global__ __launch_bounds__(THREADS, 6) void bbf_fused(
    const float* __restrict__ lines,
    const float* __restrict__ rootsx,
    const float* __restrict__ rootsy,
    const float* __restrict__ rootsz,
    const float* __restrict__ ax,
    const float* __restrict__ ay,
    const float* __restrict__ az,
    const float* __restrict__ tarx,
    const float* __restrict__ tary,
    const float* __restrict__ w,
    float* __restrict__ outx,
    float* __restrict__ outy,
    float* __restrict__ outz,
    double* __restrict__ partials)   // [NBLOCKS][2]
{
    __shared__ double redL[WPB], redR[WPB];

    const int tid  = threadIdx.x;
    const int lane = tid & 63;
    const int wix  = tid >> 6;
    const int gw   = blockIdx.x * WPB + wix;
    const int tw   = __builtin_amdgcn_readfirstlane(gw * TPW);
    const bool lastw = (tw + TPW) >= T_TOTAL;    // last wave: no halo pair

    const bool isNode = (lane < NP);
    const bool isLimb = (lane >= 1 && lane < NP);
    const int  li = isLimb ? (lane - 1) : 0;     // clamped limb index
    const int  lc = isNode ? lane : (NP - 1);    // clamped node index (loads)

    const float Lv = isLimb ? expf(lines[li % NB]) : 0.f;

    // ancestor jump table (pointer jumping 1,2,4; depth<=5; root-clamped)
    const int a1 = isLimb ? ((lane - 1) >> 1) : 0;
    const int a2 = (a1 > 0) ? ((a1 - 1) >> 1) : 0;
    const int a3 = (a2 > 0) ? ((a2 - 1) >> 1) : 0;
    const int a4 = (a3 > 0) ? ((a3 - 1) >> 1) : 0;

    // ---- batched angle loads: 17 timesteps x 3 comps, one round trip ----
    const float* axp = ax + (size_t)tw * NL + li;
    const float* ayp = ay + (size_t)tw * NL + li;
    const float* azp = az + (size_t)tw * NL + li;
    const size_t oH = lastw ? (size_t)((TPW - 1) * NL) : (size_t)(TPW * NL);
    float ax0,ay0,az0,ax1,ay1,az1,ax2,ay2,az2,ax3,ay3,az3,ax4,ay4,az4,
          ax5,ay5,az5,ax6,ay6,az6,ax7,ay7,az7,ax8,ay8,az8,ax9,ay9,az9,
          ax10,ay10,az10,ax11,ay11,az11,ax12,ay12,az12,ax13,ay13,az13,
          ax14,ay14,az14,ax15,ay15,az15,ax16,ay16,az16;
#define LOADT(K) ax##K = axp[(K)*NL]; ay##K = ayp[(K)*NL]; az##K = azp[(K)*NL];
    LOADT(0) LOADT(1) LOADT(2) LOADT(3) LOADT(4) LOADT(5) LOADT(6) LOADT(7)
    LOADT(8) LOADT(9) LOADT(10) LOADT(11) LOADT(12) LOADT(13) LOADT(14) LOADT(15)
#undef LOADT
    ax16 = axp[oH]; ay16 = ayp[oH]; az16 = azp[oH];
    // pin the whole batch (two asm stmts to stay under operand limits)
    asm volatile("" ::
        "v"(ax0),"v"(ay0),"v"(az0),"v"(ax1),"v"(ay1),"v"(az1),
        "v"(ax2),"v"(ay2),"v"(az2),"v"(ax3),"v"(ay3),"v"(az3),
        "v"(ax4),"v"(ay4),"v"(az4),"v"(ax5),"v"(ay5),"v"(az5),
        "v"(ax6),"v"(ay6),"v"(az6),"v"(ax7),"v"(ay7),"v"(az7),
        "v"(ax8),"v"(ay8),"v"(az8));
    asm volatile("" ::
        "v"(ax9),"v"(ay9),"v"(az9),"v"(ax10),"v"(ay10),"v"(az10),
        "v"(ax11),"v"(ay11),"v"(az11),"v"(ax12),"v"(ay12),"v"(az12),
        "v"(ax13),"v"(ay13),"v"(az13),"v"(ax14),"v"(ay14),"v"(az14),
        "v"(ax15),"v"(ay15),"v"(az15),"v"(ax16),"v"(ay16),"v"(az16));

    // tar/w pointers (loads sink to use; later uses are latency-covered)
    const float* txp = tarx + (size_t)tw * NP + lc;
    const float* typ = tary + (size_t)tw * NP + lc;
    const float* wp  = w    + (size_t)tw * NP + lc;
    float* oxp = outx + (size_t)tw * NP + lane;
    float* oyp = outy + (size_t)tw * NP + lane;
    float* ozp = outz + (size_t)tw * NP + lane;

    float lossAcc = 0.f, regAcc = 0.f;

#define CHAIN(K, AXK, AYK, AZK)                                               \
    float X##K, Y##K, Z##K;                                                   \
    {                                                                         \
        const float n = sqrtf(AXK*AXK + AYK*AYK + AZK*AZK) + 1e-10f;          \
        const float s = Lv / n;                                               \
        float dx = AXK * s, dy = AYK * s, dz = AZK * s;                       \
        dx += __shfl(dx, a1); dy += __shfl(dy, a1); dz += __shfl(dz, a1);     \
        dx += __shfl(dx, a2); dy += __shfl(dy, a2); dz += __shfl(dz, a2);     \
        dx += __shfl(dx, a4); dy += __shfl(dy, a4); dz += __shfl(dz, a4);     \
        const int tK = min(tw + (K), T_TOTAL - 1);                            \
        X##K = dx + rootsx[tK];                                               \
        Y##K = dy + rootsy[tK];                                               \
        Z##K = dz + rootsz[tK];                                               \
    }
#define EMIT(K)                                                               \
    if (isNode) {                                                             \
        oxp[(K)*NP] = X##K; oyp[(K)*NP] = Y##K; ozp[(K)*NP] = Z##K;           \
        const float ex = X##K - txp[(K)*NP], ey = Y##K - typ[(K)*NP];         \
        lossAcc += wp[(K)*NP] * (ex * ex + ey * ey);                          \
    }
#define REG2(KP, K)                                                           \
    if (isNode) {                                                             \
        const float d1 = X##KP - X##K, d2 = Y##KP - Y##K, d3 = Z##KP - Z##K;  \
        regAcc += d1 * d1 + d2 * d2 + d3 * d3;                                \
    }

    CHAIN(0, ax0, ay0, az0)   EMIT(0)
    CHAIN(1, ax1, ay1, az1)   EMIT(1)  REG2(0, 1)
    CHAIN(2, ax2, ay2, az2)   EMIT(2)  REG2(1, 2)
    CHAIN(3, ax3, ay3, az3)   EMIT(3)  REG2(2, 3)
    CHAIN(4, ax4, ay4, az4)   EMIT(4)  REG2(3, 4)
    CHAIN(5, ax5, ay5, az5)   EMIT(5)  REG2(4, 5)
    CHAIN(6, ax6, ay6, az6)   EMIT(6)  REG2(5, 6)
    CHAIN(7, ax7, ay7, az7)   EMIT(7)  REG2(6, 7)
    CHAIN(8, ax8, ay8, az8)   EMIT(8)  REG2(7, 8)
    CHAIN(9, ax9, ay9, az9)   EMIT(9)  REG2(8, 9)
    CHAIN(10, ax10, ay10, az10) EMIT(10) REG2(9, 10)
    CHAIN(11, ax11, ay11, az11) EMIT(11) REG2(10, 11)
    CHAIN(12, ax12, ay12, az12) EMIT(12) REG2(11, 12)
    CHAIN(13, ax13, ay13, az13) EMIT(13) REG2(12, 13)
    CHAIN(14, ax14, ay14, az14) EMIT(14) REG2(13, 14)
    CHAIN(15, ax15, ay15, az15) EMIT(15) REG2(14, 15)
    if (!lastw) {            // halo chain: pair (tw+15, tw+16) only
        CHAIN(16, ax16, ay16, az16)
        REG2(15, 16)
    }
#undef CHAIN
#undef EMIT
#undef REG2

    // wave reduce -> cross-wave LDS -> per-block partial slot
    for (int off = 32; off > 0; off >>= 1) {
        lossAcc += __shfl_down(lossAcc, off);
        regAcc  += __shfl_down(regAcc, off);
    }
    if (lane == 0) { redL[wix] = (double)lossAcc; redR[wix] = (double)regAcc; }
    __syncthreads();
    if (tid == 0) {
        double l = 0.0, r = 0.0;
        for (int i = 0; i < WPB; ++i) { l += redL[i]; r += redR[i]; }
        partials[2 * (size_t)blockIdx.x]     = l;
        partials[2 * (size_t)blockIdx.x + 1] = r;
    }
}

__global__ __launch_bounds__(1024) void bbf_finalize(
    const float* __restrict__ lines,
    const double* __restrict__ partials,
    float* __restrict__ out_total)
{
    __shared__ double rl[16], rr[16];
    const int tid = threadIdx.x;
    double l = 0.0, r = 0.0;
    for (int i = tid; i < NBLOCKS; i += 1024) {
        l += partials[2 * (size_t)i];
        r += partials[2 * (size_t)i + 1];
    }
    for (int off = 32; off > 0; off >>= 1) {
        l += __shfl_down(l, off);
        r += __shfl_down(r, off);
    }
    const int wid = tid >> 6;
    if ((tid & 63) == 0) { rl[wid] = l; rr[wid] = r; }
    __syncthreads();
    if (tid == 0) {
        double L = 0.0, R = 0.0;
        for (int i = 0; i < 16; ++i) { L += rl[i]; R += rr[i]; }
        double reg1 = 0.0;
        for (int i = 0; i < NB; ++i) reg1 += (double)expf(lines[i]);
        const double loss = L / ((double)T_TOTAL * (double)NP);
        const double reg2 = R / ((double)(T_TOTAL - 1) * (double)NP);
        *out_total = (float)(loss + 0.001 * reg1 + 0.1 * reg2);
    }
}

extern "C" void kernel_launch(void* const* d_in, const int* in_sizes, int n_in,
                              void* d_out, int out_size, void* d_ws, size_t ws_size,
                              hipStream_t stream) {
    const float* lines  = (const float*)d_in[0];
    const float* rootsx = (const float*)d_in[1];
    const float* rootsy = (const float*)d_in[2];
    const float* rootsz = (const float*)d_in[3];
    const float* ax     = (const float*)d_in[4];
    const float* ay     = (const float*)d_in[5];
    const float* az     = (const float*)d_in[6];
    const float* tarx   = (const float*)d_in[7];
    const float* tary   = (const float*)d_in[8];
    const float* w      = (const float*)d_in[9];

    float* out = (float*)d_out;
    const size_t plane = (size_t)T_TOTAL * NP;
    float* outx = out;
    float* outy = out + plane;
    float* outz = out + 2 * plane;
    float* out_total = out + 3 * plane;

    double* partials = (double*)d_ws;   // NBLOCKS*2 doubles = 50 KB; fully
                                        // rewritten every call (no memset needed)

    bbf_fused<<<NBLOCKS, THREADS, 0, stream>>>(
        lines, rootsx, rootsy, rootsz, ax, ay, az, tarx, tary, w,
        outx, outy, outz, partials);
    bbf_finalize<<<1, 1024, 0, stream>>>(lines, partials, out_total);
}

// Round 15
// 76.723 us; speedup vs baseline: 1.3112x; 1.3112x over previous
//
#include <hip/hip_runtime.h>

#define T_TOTAL 200000
#define NL 49
#define NP 50
#define NB 20
#define THREADS 256
#define WPB 4                        // waves per block
#define TPW 8                        // timesteps per wave
#define NWAVES (T_TOTAL / TPW)       // 25000
#define NBLOCKS (NWAVES / WPB)       // 6250

// Zero-barrier wave-independent kernel, ONE memory round-trip per wave:
// 27 angle + 24 tar/w loads all hand-named and asm-pinned up front, roots
// hoisted to uniform registers, then 9 register shuffle-prefix chains with
// loss/reg2/stores consuming registers only. No LDS data path.
__global__ __launch_bounds__(THREADS, 5) void bbf_fused(
    const float* __restrict__ lines,
    const float* __restrict__ rootsx,
    const float* __restrict__ rootsy,
    const float* __restrict__ rootsz,
    const float* __restrict__ ax,
    const float* __restrict__ ay,
    const float* __restrict__ az,
    const float* __restrict__ tarx,
    const float* __restrict__ tary,
    const float* __restrict__ w,
    float* __restrict__ outx,
    float* __restrict__ outy,
    float* __restrict__ outz,
    double* __restrict__ partials)   // [NBLOCKS][2]
{
    __shared__ double redL[WPB], redR[WPB];

    const int tid  = threadIdx.x;
    const int lane = tid & 63;
    const int wix  = tid >> 6;
    const int gw   = blockIdx.x * WPB + wix;
    const int tw   = __builtin_amdgcn_readfirstlane(gw * TPW);
    const bool lastw = (tw + TPW) >= T_TOTAL;    // last wave: no halo pair

    const bool isNode = (lane < NP);
    const bool isLimb = (lane >= 1 && lane < NP);
    const int  li = isLimb ? (lane - 1) : 0;     // clamped limb index
    const int  lc = isNode ? lane : (NP - 1);    // clamped node index (loads)

    const float Lv = isLimb ? expf(lines[li % NB]) : 0.f;

    // ancestor jump table (pointer jumping 1,2,4; depth<=5; root-clamped)
    const int a1 = isLimb ? ((lane - 1) >> 1) : 0;
    const int a2 = (a1 > 0) ? ((a1 - 1) >> 1) : 0;
    const int a3 = (a2 > 0) ? ((a2 - 1) >> 1) : 0;
    const int a4 = (a3 > 0) ? ((a3 - 1) >> 1) : 0;

    // ---- batched loads: 27 angles + 24 tar/w, ONE round trip ----
    const float* axp = ax + (size_t)tw * NL + li;
    const float* ayp = ay + (size_t)tw * NL + li;
    const float* azp = az + (size_t)tw * NL + li;
    const size_t o8 = lastw ? (size_t)(7 * NL) : (size_t)(8 * NL);   // clamp halo row
    float ax0,ay0,az0,ax1,ay1,az1,ax2,ay2,az2,ax3,ay3,az3,ax4,ay4,az4,
          ax5,ay5,az5,ax6,ay6,az6,ax7,ay7,az7,ax8,ay8,az8;
    ax0=axp[0*NL]; ay0=ayp[0*NL]; az0=azp[0*NL];
    ax1=axp[1*NL]; ay1=ayp[1*NL]; az1=azp[1*NL];
    ax2=axp[2*NL]; ay2=ayp[2*NL]; az2=azp[2*NL];
    ax3=axp[3*NL]; ay3=ayp[3*NL]; az3=azp[3*NL];
    ax4=axp[4*NL]; ay4=ayp[4*NL]; az4=azp[4*NL];
    ax5=axp[5*NL]; ay5=ayp[5*NL]; az5=azp[5*NL];
    ax6=axp[6*NL]; ay6=ayp[6*NL]; az6=azp[6*NL];
    ax7=axp[7*NL]; ay7=ayp[7*NL]; az7=azp[7*NL];
    ax8=axp[o8];   ay8=ayp[o8];   az8=azp[o8];

    const float* txp = tarx + (size_t)tw * NP + lc;
    const float* typ = tary + (size_t)tw * NP + lc;
    const float* wp  = w    + (size_t)tw * NP + lc;
    const float tx0=txp[0*NP], ty0=typ[0*NP], q0=wp[0*NP];
    const float tx1=txp[1*NP], ty1=typ[1*NP], q1=wp[1*NP];
    const float tx2=txp[2*NP], ty2=typ[2*NP], q2=wp[2*NP];
    const float tx3=txp[3*NP], ty3=typ[3*NP], q3=wp[3*NP];
    const float tx4=txp[4*NP], ty4=typ[4*NP], q4=wp[4*NP];
    const float tx5=txp[5*NP], ty5=typ[5*NP], q5=wp[5*NP];
    const float tx6=txp[6*NP], ty6=typ[6*NP], q6=wp[6*NP];
    const float tx7=txp[7*NP], ty7=typ[7*NP], q7=wp[7*NP];

    // pin the whole batch: all 51 values materialized here, one vmcnt drain
    asm volatile("" ::
        "v"(ax0),"v"(ay0),"v"(az0),"v"(ax1),"v"(ay1),"v"(az1),
        "v"(ax2),"v"(ay2),"v"(az2),"v"(ax3),"v"(ay3),"v"(az3),
        "v"(ax4),"v"(ay4),"v"(az4),"v"(ax5),"v"(ay5),"v"(az5),
        "v"(ax6),"v"(ay6),"v"(az6),"v"(ax7),"v"(ay7),"v"(az7),
        "v"(ax8),"v"(ay8),"v"(az8));
    asm volatile("" ::
        "v"(tx0),"v"(ty0),"v"(q0),"v"(tx1),"v"(ty1),"v"(q1),
        "v"(tx2),"v"(ty2),"v"(q2),"v"(tx3),"v"(ty3),"v"(q3),
        "v"(tx4),"v"(ty4),"v"(q4),"v"(tx5),"v"(ty5),"v"(q5),
        "v"(tx6),"v"(ty6),"v"(q6),"v"(tx7),"v"(ty7),"v"(q7));

    // roots: wave-uniform scalar loads, hoisted before the chains
    const int tH = lastw ? (tw + TPW - 1) : (tw + TPW);
    const float rx0=rootsx[tw+0], ry0=rootsy[tw+0], rz0=rootsz[tw+0];
    const float rx1=rootsx[tw+1], ry1=rootsy[tw+1], rz1=rootsz[tw+1];
    const float rx2=rootsx[tw+2], ry2=rootsy[tw+2], rz2=rootsz[tw+2];
    const float rx3=rootsx[tw+3], ry3=rootsy[tw+3], rz3=rootsz[tw+3];
    const float rx4=rootsx[tw+4], ry4=rootsy[tw+4], rz4=rootsz[tw+4];
    const float rx5=rootsx[tw+5], ry5=rootsy[tw+5], rz5=rootsz[tw+5];
    const float rx6=rootsx[tw+6], ry6=rootsy[tw+6], rz6=rootsz[tw+6];
    const float rx7=rootsx[tw+7], ry7=rootsy[tw+7], rz7=rootsz[tw+7];
    const float rx8=rootsx[tH],   ry8=rootsy[tH],   rz8=rootsz[tH];

    float* oxp = outx + (size_t)tw * NP + lane;
    float* oyp = outy + (size_t)tw * NP + lane;
    float* ozp = outz + (size_t)tw * NP + lane;

    float lossAcc = 0.f, regAcc = 0.f;

#define CHAIN(K, AXK, AYK, AZK)                                               \
    float X##K, Y##K, Z##K;                                                   \
    {                                                                         \
        const float n = sqrtf(AXK*AXK + AYK*AYK + AZK*AZK) + 1e-10f;          \
        const float s = Lv / n;                                               \
        float dx = AXK * s, dy = AYK * s, dz = AZK * s;                       \
        dx += __shfl(dx, a1); dy += __shfl(dy, a1); dz += __shfl(dz, a1);     \
        dx += __shfl(dx, a2); dy += __shfl(dy, a2); dz += __shfl(dz, a2);     \
        dx += __shfl(dx, a4); dy += __shfl(dy, a4); dz += __shfl(dz, a4);     \
        X##K = dx + rx##K;                                                    \
        Y##K = dy + ry##K;                                                    \
        Z##K = dz + rz##K;                                                    \
    }
#define EMIT(K)                                                               \
    if (isNode) {                                                             \
        oxp[(K)*NP] = X##K; oyp[(K)*NP] = Y##K; ozp[(K)*NP] = Z##K;           \
        const float ex = X##K - tx##K, ey = Y##K - ty##K;                     \
        lossAcc += q##K * (ex * ex + ey * ey);                                \
    }
#define REG2(KP, K)                                                           \
    if (isNode) {                                                             \
        const float d1 = X##KP - X##K, d2 = Y##KP - Y##K, d3 = Z##KP - Z##K;  \
        regAcc += d1 * d1 + d2 * d2 + d3 * d3;                                \
    }

    CHAIN(0, ax0, ay0, az0) EMIT(0)
    CHAIN(1, ax1, ay1, az1) EMIT(1) REG2(0, 1)
    CHAIN(2, ax2, ay2, az2) EMIT(2) REG2(1, 2)
    CHAIN(3, ax3, ay3, az3) EMIT(3) REG2(2, 3)
    CHAIN(4, ax4, ay4, az4) EMIT(4) REG2(3, 4)
    CHAIN(5, ax5, ay5, az5) EMIT(5) REG2(4, 5)
    CHAIN(6, ax6, ay6, az6) EMIT(6) REG2(5, 6)
    CHAIN(7, ax7, ay7, az7) EMIT(7) REG2(6, 7)
    if (!lastw) {            // halo chain: pair (tw+7, tw+8) only
        CHAIN(8, ax8, ay8, az8)
        REG2(7, 8)
    }
#undef CHAIN
#undef EMIT
#undef REG2

    // wave reduce -> cross-wave LDS -> per-block partial slot
    for (int off = 32; off > 0; off >>= 1) {
        lossAcc += __shfl_down(lossAcc, off);
        regAcc  += __shfl_down(regAcc, off);
    }
    if (lane == 0) { redL[wix] = (double)lossAcc; redR[wix] = (double)regAcc; }
    __syncthreads();
    if (tid == 0) {
        double l = 0.0, r = 0.0;
        for (int i = 0; i < WPB; ++i) { l += redL[i]; r += redR[i]; }
        partials[2 * (size_t)blockIdx.x]     = l;
        partials[2 * (size_t)blockIdx.x + 1] = r;
    }
}

__global__ __launch_bounds__(1024) void bbf_finalize(
    const float* __restrict__ lines,
    const double* __restrict__ partials,
    float* __restrict__ out_total)
{
    __shared__ double rl[16], rr[16];
    const int tid = threadIdx.x;
    double l = 0.0, r = 0.0;
    for (int i = tid; i < NBLOCKS; i += 1024) {
        l += partials[2 * (size_t)i];
        r += partials[2 * (size_t)i + 1];
    }
    for (int off = 32; off > 0; off >>= 1) {
        l += __shfl_down(l, off);
        r += __shfl_down(r, off);
    }
    const int wid = tid >> 6;
    if ((tid & 63) == 0) { rl[wid] = l; rr[wid] = r; }
    __syncthreads();
    if (tid == 0) {
        double L = 0.0, R = 0.0;
        for (int i = 0; i < 16; ++i) { L += rl[i]; R += rr[i]; }
        double reg1 = 0.0;
        for (int i = 0; i < NB; ++i) reg1 += (double)expf(lines[i]);
        const double loss = L / ((double)T_TOTAL * (double)NP);
        const double reg2 = R / ((double)(T_TOTAL - 1) * (double)NP);
        *out_total = (float)(loss + 0.001 * reg1 + 0.1 * reg2);
    }
}

extern "C" void kernel_launch(void* const* d_in, const int* in_sizes, int n_in,
                              void* d_out, int out_size, void* d_ws, size_t ws_size,
                              hipStream_t stream) {
    const float* lines  = (const float*)d_in[0];
    const float* rootsx = (const float*)d_in[1];
    const float* rootsy = (const float*)d_in[2];
    const float* rootsz = (const float*)d_in[3];
    const float* ax     = (const float*)d_in[4];
    const float* ay     = (const float*)d_in[5];
    const float* az     = (const float*)d_in[6];
    const float* tarx   = (const float*)d_in[7];
    const float* tary   = (const float*)d_in[8];
    const float* w      = (const float*)d_in[9];

    float* out = (float*)d_out;
    const size_t plane = (size_t)T_TOTAL * NP;
    float* outx = out;
    float* outy = out + plane;
    float* outz = out + 2 * plane;
    float* out_total = out + 3 * plane;

    double* partials = (double*)d_ws;   // NBLOCKS*2 doubles = 100 KB; fully
                                        // rewritten every call

    bbf_fused<<<NBLOCKS, THREADS, 0, stream>>>(
        lines, rootsx, rootsy, rootsz, ax, ay, az, tarx, tary, w,
        outx, outy, outz, partials);
    bbf_finalize<<<1, 1024, 0, stream>>>(lines, partials, out_total);
}

// Round 16
// 76.169 us; speedup vs baseline: 1.3207x; 1.0073x over previous
//
#include <hip/hip_runtime.h>

#define T_TOTAL 200000
#define NL 49
#define NP 50
#define NB 20
#define THREADS 256
#define WPB 4                        // waves per block
#define TPW 8                        // timesteps per wave
#define NWAVES (T_TOTAL / TPW)       // 25000
#define NBLOCKS (NWAVES / WPB)       // 6250
#define REG 456                      // per-wave LDS region: 9*50=450 +6 pad (16B mult)

// Zero-barrier kernel. Phase A: 27 pinned scalar angle loads -> 9 register
// shuffle-prefix chains -> positions into the wave's PRIVATE LDS region
// (intra-wave only => no __syncthreads, just lgkmcnt). Phase B: flat float4
// loss/reg2/outputs from own LDS region. tar/w/out all dwordx4.
__global__ __launch_bounds__(THREADS, 5) void bbf_fused(
    const float* __restrict__ lines,
    const float* __restrict__ rootsx,
    const float* __restrict__ rootsy,
    const float* __restrict__ rootsz,
    const float* __restrict__ ax,
    const float* __restrict__ ay,
    const float* __restrict__ az,
    const float* __restrict__ tarx,
    const float* __restrict__ tary,
    const float* __restrict__ w,
    float* __restrict__ outx,
    float* __restrict__ outy,
    float* __restrict__ outz,
    double* __restrict__ partials)   // [NBLOCKS][2]
{
    __shared__ __align__(16) float xsW[WPB][REG];
    __shared__ __align__(16) float ysW[WPB][REG];
    __shared__ __align__(16) float zsW[WPB][REG];
    __shared__ double redL[WPB], redR[WPB];

    const int tid  = threadIdx.x;
    const int lane = tid & 63;
    const int wix  = tid >> 6;
    const int gw   = blockIdx.x * WPB + wix;
    const int tw   = __builtin_amdgcn_readfirstlane(gw * TPW);
    const bool lastw = (tw + TPW) >= T_TOTAL;    // last wave: halo row clamps

    const bool isNode = (lane < NP);
    const bool isLimb = (lane >= 1 && lane < NP);
    const int  li = isLimb ? (lane - 1) : 0;     // clamped limb index

    const float Lv = isLimb ? expf(lines[li % NB]) : 0.f;

    // ancestor jump table (pointer jumping 1,2,4; depth<=5; root-clamped)
    const int a1 = isLimb ? ((lane - 1) >> 1) : 0;
    const int a2 = (a1 > 0) ? ((a1 - 1) >> 1) : 0;
    const int a3 = (a2 > 0) ? ((a2 - 1) >> 1) : 0;
    const int a4 = (a3 > 0) ? ((a3 - 1) >> 1) : 0;

    // ---- Phase A1: 27 pinned angle loads (one round trip) ----
    const float* axp = ax + (size_t)tw * NL + li;
    const float* ayp = ay + (size_t)tw * NL + li;
    const float* azp = az + (size_t)tw * NL + li;
    const size_t o8 = lastw ? (size_t)(7 * NL) : (size_t)(8 * NL);   // clamp halo row
    float ax0,ay0,az0,ax1,ay1,az1,ax2,ay2,az2,ax3,ay3,az3,ax4,ay4,az4,
          ax5,ay5,az5,ax6,ay6,az6,ax7,ay7,az7,ax8,ay8,az8;
    ax0=axp[0*NL]; ay0=ayp[0*NL]; az0=azp[0*NL];
    ax1=axp[1*NL]; ay1=ayp[1*NL]; az1=azp[1*NL];
    ax2=axp[2*NL]; ay2=ayp[2*NL]; az2=azp[2*NL];
    ax3=axp[3*NL]; ay3=ayp[3*NL]; az3=azp[3*NL];
    ax4=axp[4*NL]; ay4=ayp[4*NL]; az4=azp[4*NL];
    ax5=axp[5*NL]; ay5=ayp[5*NL]; az5=azp[5*NL];
    ax6=axp[6*NL]; ay6=ayp[6*NL]; az6=azp[6*NL];
    ax7=axp[7*NL]; ay7=ayp[7*NL]; az7=azp[7*NL];
    ax8=axp[o8];   ay8=ayp[o8];   az8=azp[o8];
    asm volatile("" ::
        "v"(ax0),"v"(ay0),"v"(az0),"v"(ax1),"v"(ay1),"v"(az1),
        "v"(ax2),"v"(ay2),"v"(az2),"v"(ax3),"v"(ay3),"v"(az3),
        "v"(ax4),"v"(ay4),"v"(az4),"v"(ax5),"v"(ay5),"v"(az5),
        "v"(ax6),"v"(ay6),"v"(az6),"v"(ax7),"v"(ay7),"v"(az7),
        "v"(ax8),"v"(ay8),"v"(az8));

    // roots: wave-uniform scalar loads
    const int tH = lastw ? (tw + TPW - 1) : (tw + TPW);
    const float rx0=rootsx[tw+0], ry0=rootsy[tw+0], rz0=rootsz[tw+0];
    const float rx1=rootsx[tw+1], ry1=rootsy[tw+1], rz1=rootsz[tw+1];
    const float rx2=rootsx[tw+2], ry2=rootsy[tw+2], rz2=rootsz[tw+2];
    const float rx3=rootsx[tw+3], ry3=rootsy[tw+3], rz3=rootsz[tw+3];
    const float rx4=rootsx[tw+4], ry4=rootsy[tw+4], rz4=rootsz[tw+4];
    const float rx5=rootsx[tw+5], ry5=rootsy[tw+5], rz5=rootsz[tw+5];
    const float rx6=rootsx[tw+6], ry6=rootsy[tw+6], rz6=rootsz[tw+6];
    const float rx7=rootsx[tw+7], ry7=rootsy[tw+7], rz7=rootsz[tw+7];
    const float rx8=rootsx[tH],   ry8=rootsy[tH],   rz8=rootsz[tH];

    float* xw = xsW[wix];
    float* yw = ysW[wix];
    float* zw = zsW[wix];

    // ---- Phase A2: 9 chains -> own LDS region (rows 0..8, cols 0..49) ----
    // Last wave: chain 8 == chain 7 (clamped) -> reg2 pair self-zeroes.
#define CHAIN(K, AXK, AYK, AZK)                                               \
    {                                                                         \
        const float n = sqrtf(AXK*AXK + AYK*AYK + AZK*AZK) + 1e-10f;          \
        const float s = Lv / n;                                               \
        float dx = AXK * s, dy = AYK * s, dz = AZK * s;                       \
        dx += __shfl(dx, a1); dy += __shfl(dy, a1); dz += __shfl(dz, a1);     \
        dx += __shfl(dx, a2); dy += __shfl(dy, a2); dz += __shfl(dz, a2);     \
        dx += __shfl(dx, a4); dy += __shfl(dy, a4); dz += __shfl(dz, a4);     \
        if (isNode) {                                                         \
            xw[(K)*NP + lane] = dx + rx##K;                                   \
            yw[(K)*NP + lane] = dy + ry##K;                                   \
            zw[(K)*NP + lane] = dz + rz##K;                                   \
        }                                                                     \
    }
    CHAIN(0, ax0, ay0, az0)
    CHAIN(1, ax1, ay1, az1)
    CHAIN(2, ax2, ay2, az2)
    CHAIN(3, ax3, ay3, az3)
    CHAIN(4, ax4, ay4, az4)
    CHAIN(5, ax5, ay5, az5)
    CHAIN(6, ax6, ay6, az6)
    CHAIN(7, ax7, ay7, az7)
    CHAIN(8, ax8, ay8, az8)
#undef CHAIN

    // ---- Phase B: flat float4 loss/reg2/outputs (own region; no barrier —
    //      same-wave LDS dependencies resolved by lgkmcnt) ----
    const size_t gb = (size_t)tw * NP;           // tw*200B -> 16B aligned
    const float4* tx4 = (const float4*)(tarx + gb);
    const float4* ty4 = (const float4*)(tary + gb);
    const float4* qw4 = (const float4*)(w + gb);
    float4* ox4 = (float4*)(outx + gb);
    float4* oy4 = (float4*)(outy + gb);
    float4* oz4 = (float4*)(outz + gb);

    float lossAcc = 0.f, regAcc = 0.f;
#pragma unroll
    for (int it = 0; it < 2; ++it) {
        const int c = lane + it * 64;            // 100 float4 groups per wave
        if (c < (TPW * NP) / 4) {
            const int j = c << 2;
            const float4 X  = *(const float4*)&xw[j];
            const float4 Y  = *(const float4*)&yw[j];
            const float4 Z  = *(const float4*)&zw[j];
            ox4[c] = X;
            oy4[c] = Y;
            oz4[c] = Z;
            const float4 TX = tx4[c];
            const float4 TY = ty4[c];
            const float4 WV = qw4[c];
            const float4 XA = *(const float4*)&xw[j + 48];
            const float4 XB = *(const float4*)&xw[j + 52];
            const float4 YA = *(const float4*)&yw[j + 48];
            const float4 YB = *(const float4*)&yw[j + 52];
            const float4 ZA = *(const float4*)&zw[j + 48];
            const float4 ZB = *(const float4*)&zw[j + 52];
            const float xv[4] = {X.x, X.y, X.z, X.w};
            const float yv[4] = {Y.x, Y.y, Y.z, Y.w};
            const float zv[4] = {Z.x, Z.y, Z.z, Z.w};
            const float tx[4] = {TX.x, TX.y, TX.z, TX.w};
            const float ty[4] = {TY.x, TY.y, TY.z, TY.w};
            const float qv[4] = {WV.x, WV.y, WV.z, WV.w};
            const float xn[4] = {XA.z, XA.w, XB.x, XB.y};   // floats j+50..j+53
            const float yn[4] = {YA.z, YA.w, YB.x, YB.y};
            const float zn[4] = {ZA.z, ZA.w, ZB.x, ZB.y};
#pragma unroll
            for (int e = 0; e < 4; ++e) {
                const float ex = xv[e] - tx[e];
                const float ey = yv[e] - ty[e];
                lossAcc += qv[e] * (ex * ex + ey * ey);
                const float d1 = xv[e] - xn[e];
                const float d2 = yv[e] - yn[e];
                const float d3 = zv[e] - zn[e];
                regAcc += d1 * d1 + d2 * d2 + d3 * d3;
            }
        }
    }

    // wave reduce -> cross-wave LDS -> per-block partial slot
    for (int off = 32; off > 0; off >>= 1) {
        lossAcc += __shfl_down(lossAcc, off);
        regAcc  += __shfl_down(regAcc, off);
    }
    if (lane == 0) { redL[wix] = (double)lossAcc; redR[wix] = (double)regAcc; }
    __syncthreads();
    if (tid == 0) {
        double l = 0.0, r = 0.0;
        for (int i = 0; i < WPB; ++i) { l += redL[i]; r += redR[i]; }
        partials[2 * (size_t)blockIdx.x]     = l;
        partials[2 * (size_t)blockIdx.x + 1] = r;
    }
}

__global__ __launch_bounds__(1024) void bbf_finalize(
    const float* __restrict__ lines,
    const double* __restrict__ partials,
    float* __restrict__ out_total)
{
    __shared__ double rl[16], rr[16];
    const int tid = threadIdx.x;
    double l = 0.0, r = 0.0;
    for (int i = tid; i < NBLOCKS; i += 1024) {
        l += partials[2 * (size_t)i];
        r += partials[2 * (size_t)i + 1];
    }
    for (int off = 32; off > 0; off >>= 1) {
        l += __shfl_down(l, off);
        r += __shfl_down(r, off);
    }
    const int wid = tid >> 6;
    if ((tid & 63) == 0) { rl[wid] = l; rr[wid] = r; }
    __syncthreads();
    if (tid == 0) {
        double L = 0.0, R = 0.0;
        for (int i = 0; i < 16; ++i) { L += rl[i]; R += rr[i]; }
        double reg1 = 0.0;
        for (int i = 0; i < NB; ++i) reg1 += (double)expf(lines[i]);
        const double loss = L / ((double)T_TOTAL * (double)NP);
        const double reg2 = R / ((double)(T_TOTAL - 1) * (double)NP);
        *out_total = (float)(loss + 0.001 * reg1 + 0.1 * reg2);
    }
}

extern "C" void kernel_launch(void* const* d_in, const int* in_sizes, int n_in,
                              void* d_out, int out_size, void* d_ws, size_t ws_size,
                              hipStream_t stream) {
    const float* lines  = (const float*)d_in[0];
    const float* rootsx = (const float*)d_in[1];
    const float* rootsy = (const float*)d_in[2];
    const float* rootsz = (const float*)d_in[3];
    const float* ax     = (const float*)d_in[4];
    const float* ay     = (const float*)d_in[5];
    const float* az     = (const float*)d_in[6];
    const float* tarx   = (const float*)d_in[7];
    const float* tary   = (const float*)d_in[8];
    const float* w      = (const float*)d_in[9];

    float* out = (float*)d_out;
    const size_t plane = (size_t)T_TOTAL * NP;
    float* outx = out;
    float* outy = out + plane;
    float* outz = out + 2 * plane;
    float* out_total = out + 3 * plane;

    double* partials = (double*)d_ws;   // NBLOCKS*2 doubles = 100 KB

    bbf_fused<<<NBLOCKS, THREADS, 0, stream>>>(
        lines, rootsx, rootsy, rootsz, ax, ay, az, tarx, tary, w,
        outx, outy, outz, partials);
    bbf_finalize<<<1, 1024, 0, stream>>>(lines, partials, out_total);
}